// Round 10
// baseline (4094.249 us; speedup 1.0000x reference)
//
#include <hip/hip_runtime.h>

#define NPTS 1000000
#define C 64
#define B 64
#define NBINS 8192           // B * 128 fine bins (4x4x8 per batch)
#define KTOT (64*201)        // 12864 pyramid width
#define NSLICE 125           // hist/place partition blocks
#define SLICE 8000           // NPTS / NSLICE exactly
#define A 1048576            // 1M-slot array stride in ws

typedef float f32x4 __attribute__((ext_vector_type(4)));

// ws layout (4B units):
//  binarr: int[1M] @ 0     (dead after place; S[8192*64]=2MB overlays @0)
//  earr:   f32[1M] @ A     (dead after place; Pyr[823296]=3.3MB overlays @A)
//  sidx:   int[1M] @ 2A
//  {hist2d int[125*8192]=1024000 | sexp f32[1M]} @ 3A   (hist2d dead before sexp written)
//  offs2d: int[125*8192] @ 4A
//  binstart: int[8193] @ 4A+1024000
//  ESUM:  f32[64]    @ 4A+1032200
//  acc1:  f32[16384] @ 4A+1032264   (end 20.97MB <= 21.07MB proven r9)
#define OFF_BST  (4*A + 1024000)
#define OFF_ESUM (4*A + 1032200)

__global__ __launch_bounds__(256)
void zero_kernel(float4* __restrict__ p) {
    int i = blockIdx.x * 256 + threadIdx.x;
    if (i < 16448 / 4) p[i] = make_float4(0.f, 0.f, 0.f, 0.f);
}

// Pass 1 v2: P=4 points/thread, aW1 staged in LDS (broadcast reads), k-chunked.
// r9 evidence: v1 was issue-bound (VALU-busy 135us vs 26us FMA floor) because
// all 2048 weights were re-fetched per point. Now each weight f32x4 read feeds
// 4 points' FMAs.
__global__ __launch_bounds__(256)
void mlp_kernel(const float* __restrict__ feats,
                const int* __restrict__ bidx,
                const int* __restrict__ coords,
                const float* __restrict__ aW1,
                const float* __restrict__ ab1,
                const float* __restrict__ aW2,
                const float* __restrict__ ab2,
                float* __restrict__ earr,
                int* __restrict__ binarr,
                float* __restrict__ ESUM) {
    __shared__ __align__(16) float sW[64 * 32];   // 8KB aW1
    __shared__ float sB1[32];
    __shared__ float sW2[32];
    __shared__ float sh_es[B];
    const int tid = threadIdx.x;
    for (int i = tid; i < 2048; i += 256) sW[i] = aW1[i];
    if (tid < 32) { sB1[tid] = ab1[tid]; sW2[tid] = aW2[tid]; }
    if (tid < B) sh_es[tid] = 0.f;
    __syncthreads();

    const int g0 = blockIdx.x * 256 + tid;       // 0..262143 (grid 1024)
    const int STR = 262144;
    float h[4][32];
    #pragma unroll
    for (int i = 0; i < 4; ++i)
        #pragma unroll
        for (int j = 0; j < 32; ++j) h[i][j] = sB1[j];

    #pragma unroll
    for (int kc = 0; kc < 16; ++kc) {            // 4-channel chunks
        f32x4 f[4];
        #pragma unroll
        for (int i = 0; i < 4; ++i) {
            const int p = g0 + i * STR;
            if (p < NPTS)
                f[i] = __builtin_nontemporal_load(
                    (const f32x4*)(feats + (size_t)p * C + kc * 4));
            else
                f[i] = (f32x4)(0.f);
        }
        #pragma unroll
        for (int jg = 0; jg < 8; ++jg) {         // 4-output groups
            const f32x4 w0 = *(const f32x4*)&sW[(4*kc+0)*32 + 4*jg];
            const f32x4 w1 = *(const f32x4*)&sW[(4*kc+1)*32 + 4*jg];
            const f32x4 w2 = *(const f32x4*)&sW[(4*kc+2)*32 + 4*jg];
            const f32x4 w3 = *(const f32x4*)&sW[(4*kc+3)*32 + 4*jg];
            #pragma unroll
            for (int i = 0; i < 4; ++i)
                #pragma unroll
                for (int c = 0; c < 4; ++c)
                    h[i][4*jg+c] = fmaf(f[i].x, w0[c],
                                   fmaf(f[i].y, w1[c],
                                   fmaf(f[i].z, w2[c],
                                   fmaf(f[i].w, w3[c], h[i][4*jg+c]))));
        }
    }
    const float b2 = ab2[0];
    #pragma unroll
    for (int i = 0; i < 4; ++i) {
        const int p = g0 + i * STR;
        if (p < NPTS) {
            float raw = b2;
            #pragma unroll
            for (int j = 0; j < 32; ++j) raw = fmaf(fmaxf(h[i][j], 0.f), sW2[j], raw);
            const float e = expf(raw);           // softmax max-shift cancels analytically
            const int b  = bidx[p];
            const int cx = coords[3*p], cy = coords[3*p+1], cz = coords[3*p+2];
            earr[p]   = e;
            binarr[p] = b * 128 + ((cx >> 6) << 5) + ((cy >> 6) << 3) + (cz >> 5);
            atomicAdd(&sh_es[b], e);
        }
    }
    __syncthreads();
    if (tid < B) atomicAdd(&ESUM[tid], sh_es[tid]);
}

// Per-slice LDS histogram (no global atomics).
__global__ __launch_bounds__(256)
void hist_kernel(const int* __restrict__ binarr, int* __restrict__ hist2d) {
    __shared__ int h[NBINS];
    const int tid = threadIdx.x;
    for (int i = tid; i < NBINS; i += 256) h[i] = 0;
    __syncthreads();
    const int lo = blockIdx.x * SLICE, hi = lo + SLICE;
    for (int p = lo + tid; p < hi; p += 256) atomicAdd(&h[binarr[p]], 1);
    __syncthreads();
    for (int i = tid; i < NBINS; i += 256) hist2d[blockIdx.x * NBINS + i] = h[i];
}

// counts[bin] = sum over slices (into binstart[], scanned in place by scanB)
__global__ __launch_bounds__(256)
void scanA_kernel(const int* __restrict__ hist2d, int* __restrict__ binstart) {
    const int gid = blockIdx.x * 256 + threadIdx.x;
    if (gid < NBINS) {
        int s = 0;
        for (int b = 0; b < NSLICE; ++b) s += hist2d[b * NBINS + gid];
        binstart[gid] = s;
    }
}

// exclusive scan over 8192 counts, in place; binstart[8192] = NPTS
__global__ __launch_bounds__(256)
void scanB_kernel(int* __restrict__ binstart) {
    __shared__ int c[NBINS];
    __shared__ int part[257];
    const int tid = threadIdx.x;
    for (int i = tid; i < NBINS; i += 256) c[i] = binstart[i];
    __syncthreads();
    const int base = tid * 32;
    int s = 0;
    #pragma unroll
    for (int j = 0; j < 32; ++j) s += c[base + j];
    part[tid + 1] = s;
    if (tid == 0) part[0] = 0;
    __syncthreads();
    if (tid == 0) for (int i = 1; i <= 256; ++i) part[i] += part[i - 1];
    __syncthreads();
    int off = part[tid];
    #pragma unroll
    for (int j = 0; j < 32; ++j) { const int t = c[base + j]; binstart[base + j] = off; off += t; }
    if (tid == 255) binstart[NBINS] = off;   // == NPTS
}

// offs2d[slice][bin] = binstart[bin] + earlier slices' counts
__global__ __launch_bounds__(256)
void scanC_kernel(const int* __restrict__ hist2d, const int* __restrict__ binstart,
                  int* __restrict__ offs2d) {
    const int gid = blockIdx.x * 256 + threadIdx.x;
    if (gid < NBINS) {
        int off = binstart[gid];
        for (int b = 0; b < NSLICE; ++b) {
            offs2d[b * NBINS + gid] = off;
            off += hist2d[b * NBINS + gid];
        }
    }
}

// Placement: LDS cursors with exact global offsets -> no global atomics.
__global__ __launch_bounds__(256)
void place_kernel(const int* __restrict__ binarr, const float* __restrict__ earr,
                  const int* __restrict__ offs2d,
                  int* __restrict__ sidx, float* __restrict__ sexp) {
    __shared__ int cur[NBINS];
    const int tid = threadIdx.x;
    for (int i = tid; i < NBINS; i += 256) cur[i] = offs2d[blockIdx.x * NBINS + i];
    __syncthreads();
    const int lo = blockIdx.x * SLICE, hi = lo + SLICE;
    for (int p = lo + tid; p < hi; p += 256) {
        const int b = binarr[p];
        const int pos = atomicAdd(&cur[b], 1);       // LDS atomic only
        sidx[pos] = p;
        sexp[pos] = earr[p];
    }
}

// Segmented reduction: one wave per bin, lane = channel. Coalesced 256B row
// gathers, 8 independent FMA chains, single plain store. Zero atomics.
__global__ __launch_bounds__(256)
void reduce_kernel(const float* __restrict__ feats,
                   const int* __restrict__ sidx, const float* __restrict__ sexp,
                   const int* __restrict__ binstart, float* __restrict__ S) {
    const int tid = threadIdx.x;
    const int lane = tid & 63;
    const int bin = blockIdx.x * 4 + (tid >> 6);
    const int start = binstart[bin], end = binstart[bin + 1];
    float a[8];
    #pragma unroll
    for (int i = 0; i < 8; ++i) a[i] = 0.f;
    int k = start;
    for (; k + 7 < end; k += 8) {
        #pragma unroll
        for (int u = 0; u < 8; ++u) {
            const int   iu = sidx[k + u];
            const float eu = sexp[k + u];
            const float vu = __builtin_nontemporal_load(feats + (size_t)iu * C + lane);
            a[u] = fmaf(vu, eu, a[u]);
        }
    }
    for (; k < end; ++k) {
        const float v = __builtin_nontemporal_load(feats + (size_t)sidx[k] * C + lane);
        a[0] = fmaf(v, sexp[k], a[0]);
    }
    S[(size_t)bin * C + lane] = ((a[0]+a[1])+(a[2]+a[3])) + ((a[4]+a[5])+(a[6]+a[7]));
}

// Aggregate fine bins -> 4 nested levels, normalize by exp-sum and counts.
__global__ __launch_bounds__(256)
void finalize_kernel(const float* __restrict__ S, const int* __restrict__ binstart,
                     const float* __restrict__ ESUM, float* __restrict__ P) {
    __shared__ float sS[128 * C];               // 32 KB
    __shared__ float sc[128];
    const int b = blockIdx.x;
    const int tid = threadIdx.x;
    for (int i = tid; i < 128 * C; i += 256) sS[i] = S[(size_t)b * 128 * C + i];
    for (int i = tid; i < 128; i += 256)
        sc[i] = (float)(binstart[b * 128 + i + 1] - binstart[b * 128 + i]);
    __syncthreads();
    const float inv_es = 1.0f / ESUM[b];
    float* Pb = P + (size_t)b * KTOT;
    const int lane = tid & 63;
    const int wv = tid >> 6;
    // L3 (4,4,8) @4672
    for (int bin = wv; bin < 128; bin += 4) {
        const float c = sc[bin];
        Pb[4672 + bin*C + lane] = (c > 0.f) ? sS[bin*C + lane] * inv_es / fmaxf(c, 1.f) : 0.f;
    }
    // L2 (4,4,4) @576
    for (int bin = wv; bin < 64; bin += 4) {
        const int x = bin >> 4, y = (bin >> 2) & 3, z = bin & 3;
        const int f0 = x*32 + y*8 + 2*z;
        const float c = sc[f0] + sc[f0 + 1];
        const float s = sS[f0*C + lane] + sS[(f0+1)*C + lane];
        Pb[576 + bin*C + lane] = (c > 0.f) ? s * inv_es / fmaxf(c, 1.f) : 0.f;
    }
    // L1 (2,2,2) @64
    for (int bin = wv; bin < 8; bin += 4) {
        const int x = bin >> 2, y = (bin >> 1) & 1, z = bin & 1;
        float c = 0.f, s = 0.f;
        for (int dx = 0; dx < 2; ++dx)
            for (int dy = 0; dy < 2; ++dy)
                for (int dz = 0; dz < 4; ++dz) {
                    const int f = (2*x+dx)*32 + (2*y+dy)*8 + (4*z+dz);
                    c += sc[f]; s += sS[f*C + lane];
                }
        Pb[64 + bin*C + lane] = (c > 0.f) ? s * inv_es / fmaxf(c, 1.f) : 0.f;
    }
    // L0 (1,1,1) @0
    if (wv == 0) {
        float c = 0.f, s = 0.f;
        for (int f = 0; f < 128; ++f) { c += sc[f]; s += sS[f*C + lane]; }
        Pb[lane] = (c > 0.f) ? s * inv_es / fmaxf(c, 1.f) : 0.f;
    }
}

// acc partial: P[64,12864] @ W1[12864,256], split-K with atomic reduce.
__global__ __launch_bounds__(256)
void gemm1_kernel(const float* __restrict__ P, const float* __restrict__ W1,
                  float* __restrict__ acc) {
    __shared__ float sP[64 * 128];
    const int jb = blockIdx.x;                  // 0..3
    const int kb = blockIdx.y;                  // 0..100
    const int k0 = kb * 128;
    const int kw = min(128, KTOT - k0);
    const int tid = threadIdx.x;
    for (int i = tid; i < 64 * 32; i += 256) {
        const int row = i >> 5, c4 = i & 31;
        if (c4 * 4 < kw)
            *(float4*)&sP[row*128 + c4*4] =
                *(const float4*)&P[(size_t)row * KTOT + k0 + c4*4];
    }
    __syncthreads();
    const int j = jb * 64 + (tid & 63);
    const int g = tid >> 6;
    float a[16];
    #pragma unroll
    for (int i = 0; i < 16; ++i) a[i] = 0.f;
    for (int k4 = 0; k4 < (kw >> 2); ++k4) {
        const int k = 4 * k4;
        const float w0 = W1[(size_t)(k0+k+0)*256 + j];
        const float w1 = W1[(size_t)(k0+k+1)*256 + j];
        const float w2 = W1[(size_t)(k0+k+2)*256 + j];
        const float w3 = W1[(size_t)(k0+k+3)*256 + j];
        #pragma unroll
        for (int i = 0; i < 16; ++i) {
            const float4 pv = *(const float4*)&sP[(g + 4*i)*128 + k];
            a[i] = fmaf(pv.x, w0, fmaf(pv.y, w1, fmaf(pv.z, w2, fmaf(pv.w, w3, a[i]))));
        }
    }
    #pragma unroll
    for (int i = 0; i < 16; ++i)
        atomicAdd(&acc[(g + 4*i)*256 + j], a[i]);
}

// out = relu(acc + pb1) @ W2 + pb2
__global__ __launch_bounds__(256)
void gemm2_kernel(const float* __restrict__ acc, const float* __restrict__ pb1,
                  const float* __restrict__ W2, const float* __restrict__ pb2,
                  float* __restrict__ out) {
    __shared__ float R[256];
    const int b = blockIdx.x, j = threadIdx.x;
    R[j] = fmaxf(acc[b*256 + j] + pb1[j], 0.f);
    __syncthreads();
    float s = pb2[j];
    #pragma unroll 8
    for (int m = 0; m < 256; ++m) s = fmaf(R[m], W2[m*256 + j], s);
    out[b*256 + j] = s;
}

extern "C" void kernel_launch(void* const* d_in, const int* in_sizes, int n_in,
                              void* d_out, int out_size, void* d_ws, size_t ws_size,
                              hipStream_t stream) {
    const float* feats  = (const float*)d_in[0];
    const int*   bidx   = (const int*)d_in[1];
    const int*   coords = (const int*)d_in[2];
    const float* aW1 = (const float*)d_in[4];
    const float* ab1 = (const float*)d_in[5];
    const float* aW2 = (const float*)d_in[6];
    const float* ab2 = (const float*)d_in[7];
    const float* pW1 = (const float*)d_in[8];
    const float* pb1 = (const float*)d_in[9];
    const float* pW2 = (const float*)d_in[10];
    const float* pb2 = (const float*)d_in[11];
    float* out = (float*)d_out;
    float* ws  = (float*)d_ws;

    int*   binarr   = (int*)ws;
    float* earr     = ws + A;
    int*   sidx     = (int*)(ws + 2*A);
    int*   hist2d   = (int*)(ws + 3*A);             // overlays sexp (disjoint live ranges)
    float* sexp     = ws + 3*A;
    int*   offs2d   = (int*)(ws + 4*A);
    int*   binstart = (int*)(ws + OFF_BST);
    float* ESUM     = ws + OFF_ESUM;
    float* acc1     = ESUM + 64;
    float* S        = ws;                           // overlay on binarr (dead after place)
    float* Pyr      = ws + A;                       // overlay on earr (dead after place)

    hipLaunchKernelGGL(zero_kernel, dim3(17), dim3(256), 0, stream, (float4*)(ws + OFF_ESUM));
    hipLaunchKernelGGL(mlp_kernel, dim3(1024), dim3(256), 0, stream,
                       feats, bidx, coords, aW1, ab1, aW2, ab2, earr, binarr, ESUM);
    hipLaunchKernelGGL(hist_kernel, dim3(NSLICE), dim3(256), 0, stream, binarr, hist2d);
    hipLaunchKernelGGL(scanA_kernel, dim3(32), dim3(256), 0, stream, hist2d, binstart);
    hipLaunchKernelGGL(scanB_kernel, dim3(1), dim3(256), 0, stream, binstart);
    hipLaunchKernelGGL(scanC_kernel, dim3(32), dim3(256), 0, stream, hist2d, binstart, offs2d);
    hipLaunchKernelGGL(place_kernel, dim3(NSLICE), dim3(256), 0, stream,
                       binarr, earr, offs2d, sidx, sexp);
    hipLaunchKernelGGL(reduce_kernel, dim3(2048), dim3(256), 0, stream,
                       feats, sidx, sexp, binstart, S);
    hipLaunchKernelGGL(finalize_kernel, dim3(64), dim3(256), 0, stream, S, binstart, ESUM, Pyr);
    hipLaunchKernelGGL(gemm1_kernel, dim3(4, 101), dim3(256), 0, stream, Pyr, pW1, acc1);
    hipLaunchKernelGGL(gemm2_kernel, dim3(64), dim3(256), 0, stream, acc1, pb1, pW2, pb2, out);
}